// Round 4
// baseline (10849.094 us; speedup 1.0000x reference)
//
#include <hip/hip_runtime.h>
#include <math.h>

#define DT_C 0.042f
#define Bn 128
#define Tn 1024
#define In 64
#define Hn 512

#define CL 8     // WGs per cluster (k-split factor)
#define NC 128   // clusters; grid = NC*CL = 1024 = exactly 4 WG/CU (32-wave HW cap)
#define BB 1     // batches per cluster
#define KS 64    // k-rows (and owned cols) per WG
#define FLAG_STRIDE 16  // uints (64 B) per flag

// ---------------------------------------------------------------------------
// Kernel A: u[b,t,h] = bias[h] + sum_i x[b,t,i] * x2h[i,h]  (in-place in d_out)
// ---------------------------------------------------------------------------
#define ROWS_A 256
__global__ __launch_bounds__(512) void ron_proj_kernel(
    const float* __restrict__ x, const float* __restrict__ x2h,
    const float* __restrict__ bias, float* __restrict__ u)
{
    __shared__ float xs[8 * In];
    const int h = threadIdx.x;
    const long row0 = (long)blockIdx.x * ROWS_A;

    float w[In];
    #pragma unroll
    for (int i = 0; i < In; ++i) w[i] = x2h[i * Hn + h];
    const float bh = bias[h];

    for (int r8 = 0; r8 < ROWS_A; r8 += 8) {
        __syncthreads();
        xs[h] = x[(row0 + r8) * In + h];
        __syncthreads();
        float acc[8];
        #pragma unroll
        for (int r = 0; r < 8; ++r) acc[r] = bh;
        #pragma unroll
        for (int i = 0; i < In; ++i) {
            #pragma unroll
            for (int r = 0; r < 8; ++r)
                acc[r] = fmaf(xs[r * In + i], w[i], acc[r]);
        }
        #pragma unroll
        for (int r = 0; r < 8; ++r)
            u[(row0 + r8 + r) * Hn + h] = acc[r];
    }
}

// ---------------------------------------------------------------------------
// Kernel B: k-split cluster scan. 1024 WGs = 128 clusters x 8 WGs = 4 WG/CU
// (exact hardware capacity: 4 x 8 waves = 32 waves/CU; grid == capacity so
// packing is uniform and co-residency is guaranteed — no LDS pad needed).
// The 4 WGs resident on a CU belong to 4 DIFFERENT clusters (independent
// sync domains): their compute fills each other's scatter/flag/poll/gather
// latency. R3 (2 domains) gave 43% occ / 2.6 ms; this pushes the same
// mechanism to the HW limit.
//
// WG j of cluster c: h2h rows [64j,64j+64), owns hy/hz cols [64j,64j+64)
// for the cluster's single batch.
//
// Sync protocol is RELAXED-only (R1: release/acquire cache maintenance = 2.7x):
//  - all inter-WG data (chunks, flags) moves via agent-scope ATOMIC ops;
//  - producer ordering: chunk stores -> B1 __syncthreads (drains vmcnt) -> flag;
//  - consumer ordering: wave-0 all-lane poll -> (in-wave control dep) -> gather.
//    No barrier between poll and gather: the updater is exactly wave 0, and
//    the gather loads are control-dependent on the poll result (R2 validated
//    this poll pattern's correctness).
// Cross-step safety: flag(t+1) follows B1(t+1) > B3(t) > gather(t) for every
// mate, so a parity buffer is never overwritten before its readers are done.
//
// NOTE (R2 post-mortem): do NOT asm-pin w_r[] — the allocator spills it to
// scratch instead of keeping it resident; the default L2 remat-reload wins.
// ---------------------------------------------------------------------------
__global__ __launch_bounds__(512, 8) void ron_scan_kernel(
    const float* __restrict__ h2h,
    const float* __restrict__ gamma,
    const float* __restrict__ eps,
    float* __restrict__ out,
    unsigned* __restrict__ flags,   // [NC*CL*FLAG_STRIDE], zeroed by memset
    float* __restrict__ chunks)     // [NC][2][CL dest][CL src][BB][KS]
{
    __shared__ __align__(16) float hyL[BB][KS];

    const int tid = threadIdx.x;
    const int w   = blockIdx.x;
    const int j   = w >> 7;    // slice id 0..7 (mates share bid%8 -> same XCD)
    const int c   = w & 127;   // cluster id 0..127

    const int col = tid;       // partial-phase mapping: one thread per column
    const int uoc = tid & 63;  // update-phase mapping
    const bool upd = (tid < 64);   // exactly wave 0

    // --- weight slice: w_r[k] = h2h[(64j+k)*512 + col] (compiler remats from L2) ---
    float w_r[KS];
    #pragma unroll
    for (int k = 0; k < KS; ++k)
        w_r[k] = h2h[(size_t)(KS * j + k) * Hn + col];

    float hy = 0.f, hz = 0.f, g = 0.f, e = 0.f;
    size_t up_off = 0;
    if (upd) {
        g = gamma[KS * j + uoc];
        e = eps[KS * j + uoc];
        up_off = (size_t)c * Tn * Hn + KS * j + uoc;
        hyL[0][uoc] = 0.f;
    }
    const int fbase  = c * CL * FLAG_STRIDE;
    const int i_dest = col >> 6;
    const int oc_p   = col & 63;
    bool dead = false;
    __syncthreads();

    for (int t = 0; t < Tn; ++t) {
        const int par = t & 1;

        // prefetch u early (consumed after the exchange)
        float uval = 0.f;
        if (upd) uval = out[up_off + (size_t)t * Hn];

        // --- partial: own k-slice, all 512 cols, 1 batch ---
        float a0 = 0.f;
        #pragma unroll
        for (int g4 = 0; g4 < KS / 4; ++g4) {
            const float4 h0 = *(const float4*)&hyL[0][4 * g4];
            a0 = fmaf(h0.x, w_r[4*g4+0], a0);
            a0 = fmaf(h0.y, w_r[4*g4+1], a0);
            a0 = fmaf(h0.z, w_r[4*g4+2], a0);
            a0 = fmaf(h0.w, w_r[4*g4+3], a0);
        }

        // --- scatter chunk to cluster mates (agent-scope atomic store) ---
        {
            float* chp = chunks +
                ((((size_t)(c * 2 + par) * CL + i_dest) * CL + j) * BB) * KS + oc_p;
            __hip_atomic_store(&chp[0], a0, __ATOMIC_RELAXED, __HIP_MEMORY_SCOPE_AGENT);
        }
        __syncthreads();  // B1: drains each wave's vmcnt; all chunk stores complete
        if (tid == 0)
            __hip_atomic_store(&flags[fbase + j * FLAG_STRIDE], (unsigned)(t + 1),
                               __ATOMIC_RELAXED, __HIP_MEMORY_SCOPE_AGENT);

        // --- wave-0 all-lane poll; gather is control-dependent, no barrier ---
        if (upd && !dead) {
            const unsigned tgt = (unsigned)(t + 1);
            const unsigned* fp = &flags[fbase + (tid & (CL - 1)) * FLAG_STRIDE];
            int guard = 0;
            unsigned v;
            do {
                v = __hip_atomic_load(fp, __ATOMIC_RELAXED, __HIP_MEMORY_SCOPE_AGENT);
                if (++guard > (1 << 18)) { dead = true; break; }  // no-hang bailout
            } while (__any(v < tgt));
        }

        // --- gather 8 partials for own columns, update state (wave 0 only) ---
        if (upd) {
            const float* rdp = chunks +
                ((((size_t)(c * 2 + par) * CL + j) * CL) * BB) * KS + uoc;
            float wsum = 0.f;
            #pragma unroll
            for (int p = 0; p < CL; ++p)
                wsum += __hip_atomic_load(&rdp[(size_t)p * BB * KS],
                                          __ATOMIC_RELAXED, __HIP_MEMORY_SCOPE_AGENT);
            hz += DT_C * (tanhf(uval + wsum) - g * hy - e * hz);
            hy += DT_C * hz;
            out[up_off + (size_t)t * Hn] = hy;
            hyL[0][uoc] = hy;
        }
        __syncthreads();  // B3: hyL visible for next step's partial
    }

    if (upd)
        out[(size_t)Bn * Tn * Hn + (size_t)c * Hn + KS * j + uoc] = hy;
}

// ---------------------------------------------------------------------------
extern "C" void kernel_launch(void* const* d_in, const int* in_sizes, int n_in,
                              void* d_out, int out_size, void* d_ws, size_t ws_size,
                              hipStream_t stream) {
    const float* x     = (const float*)d_in[0];
    const float* x2h   = (const float*)d_in[1];
    const float* h2h   = (const float*)d_in[2];
    const float* bias  = (const float*)d_in[3];
    const float* gamma = (const float*)d_in[4];
    const float* eps   = (const float*)d_in[5];
    float* out = (float*)d_out;

    unsigned* flags = (unsigned*)d_ws;                        // 64 KB
    float*    chunks = (float*)((char*)d_ws + 65536);         // 4 MB

    // zero the step flags (chunks are flag-guarded, no init needed)
    hipMemsetAsync(d_ws, 0, NC * CL * FLAG_STRIDE * sizeof(unsigned), stream);

    ron_proj_kernel<<<(Bn * Tn) / ROWS_A, 512, 0, stream>>>(x, x2h, bias, out);
    ron_scan_kernel<<<NC * CL, 512, 0, stream>>>(h2h, gamma, eps, out, flags, chunks);
}

// Round 5
// 4383.751 us; speedup vs baseline: 2.4748x; 2.4748x over previous
//
#include <hip/hip_runtime.h>
#include <math.h>

#define DT_C 0.042f
#define Bn 128
#define Tn 1024
#define In 64
#define Hn 512

#define CL 16    // WGs per cluster (k-split factor)
#define NC 32    // clusters; grid = NC*CL = 512; LDS caps 2 WG/CU (2 domains/CU)
#define BB 4     // batches per cluster
#define KS 32    // k-rows (and owned cols) per WG -> 64 KB LDS weight patch
#define FLAG_STRIDE 16  // uints (64 B) per flag

// ---------------------------------------------------------------------------
// Kernel A: u[b,t,h] = bias[h] + sum_i x[b,t,i] * x2h[i,h]  (in-place in d_out)
// ---------------------------------------------------------------------------
#define ROWS_A 256
__global__ __launch_bounds__(512) void ron_proj_kernel(
    const float* __restrict__ x, const float* __restrict__ x2h,
    const float* __restrict__ bias, float* __restrict__ u)
{
    __shared__ float xs[8 * In];
    const int h = threadIdx.x;
    const long row0 = (long)blockIdx.x * ROWS_A;

    float w[In];
    #pragma unroll
    for (int i = 0; i < In; ++i) w[i] = x2h[i * Hn + h];
    const float bh = bias[h];

    for (int r8 = 0; r8 < ROWS_A; r8 += 8) {
        __syncthreads();
        xs[h] = x[(row0 + r8) * In + h];
        __syncthreads();
        float acc[8];
        #pragma unroll
        for (int r = 0; r < 8; ++r) acc[r] = bh;
        #pragma unroll
        for (int i = 0; i < In; ++i) {
            #pragma unroll
            for (int r = 0; r < 8; ++r)
                acc[r] = fmaf(xs[r * In + i], w[i], acc[r]);
        }
        #pragma unroll
        for (int r = 0; r < 8; ++r)
            u[(row0 + r8 + r) * Hn + h] = acc[r];
    }
}

// ---------------------------------------------------------------------------
// Kernel B: k-split cluster scan with LDS-RESIDENT WEIGHTS.
// 512 WGs = 32 clusters x 16 WGs; LDS (64.5 KB/WG) caps residency at 2 WG/CU,
// and the two resident WGs are different clusters (independent sync domains).
//
// R4 post-mortem: per-step weight remat from L2 was the session-long
// bottleneck (R3: 64 MB/step = 1.9 us L2-BW floor; R4: 128 MB/step + L2
// thrash -> 13x HBM fetch). Fix: KS=32 k-slices so the 32x512 f32 weight
// patch (64 KB) lives in LDS, loaded ONCE before the t-loop. Zero per-step
// weight traffic to L2/HBM.
//
// WG j of cluster c: h2h rows [32j,32j+32), owns hy/hz cols [32j,32j+32)
// for the cluster's 4 batches (update slots = 128 threads = 2 waves).
//
// Sync protocol RELAXED-only (R1: release/acquire cache maintenance = 2.7x):
//  - producer: chunk stores -> B1 __syncthreads (drains vmcnt) -> flag store;
//  - consumer: per-wave all-lane flag poll -> (in-wave control dep) -> gather.
// Overwrite safety: scatter(t+2) follows poll(t+1) which requires all mates'
// flag(t+1) >= t+1, which follows their B1(t+1) > B3(t) > gather(t). QED.
//
// NOTE (R2): never asm-pin register arrays — allocator spills to scratch.
// ---------------------------------------------------------------------------
__global__ __launch_bounds__(512, 4) void ron_scan_kernel(
    const float* __restrict__ h2h,
    const float* __restrict__ gamma,
    const float* __restrict__ eps,
    float* __restrict__ out,
    unsigned* __restrict__ flags,   // [NC*CL*FLAG_STRIDE], zeroed by memset
    float* __restrict__ chunks)     // [NC][2][CL dest][CL src][BB][KS]
{
    __shared__ __align__(16) float wLDS[KS * Hn];   // 64 KB weight patch
    __shared__ __align__(16) float hyL[BB][KS];     // 512 B

    const int tid = threadIdx.x;
    const int w   = blockIdx.x;
    const int j   = w >> 5;    // slice id 0..15 (mates share bid%8 -> same XCD)
    const int c   = w & 31;    // cluster id 0..31

    const int col = tid;       // partial-phase mapping: one thread per column

    // --- stage weight patch into LDS (once): wLDS4[kg*Hn + col] = 4 k-rows ---
    #pragma unroll
    for (int kg = 0; kg < KS / 4; ++kg) {
        float4 wv;
        wv.x = h2h[(size_t)(KS * j + 4 * kg + 0) * Hn + col];
        wv.y = h2h[(size_t)(KS * j + 4 * kg + 1) * Hn + col];
        wv.z = h2h[(size_t)(KS * j + 4 * kg + 2) * Hn + col];
        wv.w = h2h[(size_t)(KS * j + 4 * kg + 3) * Hn + col];
        ((float4*)wLDS)[kg * Hn + col] = wv;   // lanes consecutive: conflict-free
    }

    const int ubb = tid >> 5;  // update-phase mapping: tid<128 -> (bb, oc)
    const int uoc = tid & 31;
    const bool upd = (tid < 128);   // exactly waves 0 and 1

    float hy = 0.f, hz = 0.f, g = 0.f, e = 0.f;
    size_t up_off = 0;
    if (upd) {
        g = gamma[KS * j + uoc];
        e = eps[KS * j + uoc];
        up_off = (size_t)(BB * c + ubb) * Tn * Hn + KS * j + uoc;
        hyL[ubb][uoc] = 0.f;
    }
    const int fbase  = c * CL * FLAG_STRIDE;
    const int i_dest = col >> 5;
    const int oc_p   = col & 31;
    bool dead = false;
    __syncthreads();   // weights staged + hyL initialized

    for (int t = 0; t < Tn; ++t) {
        const int par = t & 1;

        // prefetch u early (consumed after the exchange)
        float uval = 0.f;
        if (upd) uval = out[up_off + (size_t)t * Hn];

        // --- partial: own 32-k slice, all 512 cols, 4 batches (LDS weights) ---
        float a0 = 0.f, a1 = 0.f, a2 = 0.f, a3 = 0.f;
        #pragma unroll
        for (int kg = 0; kg < KS / 4; ++kg) {
            const float4 wv = ((const float4*)wLDS)[kg * Hn + col];
            const float4 h0 = *(const float4*)&hyL[0][4 * kg];
            const float4 h1 = *(const float4*)&hyL[1][4 * kg];
            const float4 h2 = *(const float4*)&hyL[2][4 * kg];
            const float4 h3 = *(const float4*)&hyL[3][4 * kg];
            a0 = fmaf(h0.x, wv.x, a0); a1 = fmaf(h1.x, wv.x, a1);
            a2 = fmaf(h2.x, wv.x, a2); a3 = fmaf(h3.x, wv.x, a3);
            a0 = fmaf(h0.y, wv.y, a0); a1 = fmaf(h1.y, wv.y, a1);
            a2 = fmaf(h2.y, wv.y, a2); a3 = fmaf(h3.y, wv.y, a3);
            a0 = fmaf(h0.z, wv.z, a0); a1 = fmaf(h1.z, wv.z, a1);
            a2 = fmaf(h2.z, wv.z, a2); a3 = fmaf(h3.z, wv.z, a3);
            a0 = fmaf(h0.w, wv.w, a0); a1 = fmaf(h1.w, wv.w, a1);
            a2 = fmaf(h2.w, wv.w, a2); a3 = fmaf(h3.w, wv.w, a3);
        }

        // --- scatter chunks to the 16 cluster mates (agent-scope stores) ---
        {
            float* chp = chunks +
                ((((size_t)(c * 2 + par) * CL + i_dest) * CL + j) * BB) * KS + oc_p;
            __hip_atomic_store(&chp[0 * KS], a0, __ATOMIC_RELAXED, __HIP_MEMORY_SCOPE_AGENT);
            __hip_atomic_store(&chp[1 * KS], a1, __ATOMIC_RELAXED, __HIP_MEMORY_SCOPE_AGENT);
            __hip_atomic_store(&chp[2 * KS], a2, __ATOMIC_RELAXED, __HIP_MEMORY_SCOPE_AGENT);
            __hip_atomic_store(&chp[3 * KS], a3, __ATOMIC_RELAXED, __HIP_MEMORY_SCOPE_AGENT);
        }
        __syncthreads();  // B1: drains each wave's vmcnt; all chunk stores complete
        if (tid == 0)
            __hip_atomic_store(&flags[fbase + j * FLAG_STRIDE], (unsigned)(t + 1),
                               __ATOMIC_RELAXED, __HIP_MEMORY_SCOPE_AGENT);

        // --- per-wave all-lane poll (updater waves 0,1); gather is
        //     control-dependent within the wave, no barrier needed ---
        if (upd && !dead) {
            const unsigned tgt = (unsigned)(t + 1);
            const unsigned* fp = &flags[fbase + (tid & (CL - 1)) * FLAG_STRIDE];
            int guard = 0;
            unsigned v;
            do {
                v = __hip_atomic_load(fp, __ATOMIC_RELAXED, __HIP_MEMORY_SCOPE_AGENT);
                if (++guard > (1 << 18)) { dead = true; break; }  // no-hang bailout
            } while (__any(v < tgt));
        }

        // --- gather 16 partials for own (bb, col) slot, update state ---
        if (upd) {
            const float* rdp = chunks +
                ((size_t)(c * 2 + par) * CL + j) * (CL * BB * KS) + ubb * KS + uoc;
            float wsum = 0.f;
            #pragma unroll
            for (int p = 0; p < CL; ++p)
                wsum += __hip_atomic_load(&rdp[(size_t)p * BB * KS],
                                          __ATOMIC_RELAXED, __HIP_MEMORY_SCOPE_AGENT);
            hz += DT_C * (tanhf(uval + wsum) - g * hy - e * hz);
            hy += DT_C * hz;
            out[up_off + (size_t)t * Hn] = hy;
            hyL[ubb][uoc] = hy;
        }
        __syncthreads();  // B3: hyL visible for next step's partial
    }

    if (upd)
        out[(size_t)Bn * Tn * Hn + (size_t)(BB * c + ubb) * Hn + KS * j + uoc] = hy;
}

// ---------------------------------------------------------------------------
extern "C" void kernel_launch(void* const* d_in, const int* in_sizes, int n_in,
                              void* d_out, int out_size, void* d_ws, size_t ws_size,
                              hipStream_t stream) {
    const float* x     = (const float*)d_in[0];
    const float* x2h   = (const float*)d_in[1];
    const float* h2h   = (const float*)d_in[2];
    const float* bias  = (const float*)d_in[3];
    const float* gamma = (const float*)d_in[4];
    const float* eps   = (const float*)d_in[5];
    float* out = (float*)d_out;

    unsigned* flags = (unsigned*)d_ws;                        // 32 KB
    float*    chunks = (float*)((char*)d_ws + 65536);         // 8 MB

    // zero the step flags (chunks are flag-guarded, no init needed)
    hipMemsetAsync(d_ws, 0, NC * CL * FLAG_STRIDE * sizeof(unsigned), stream);

    ron_proj_kernel<<<(Bn * Tn) / ROWS_A, 512, 0, stream>>>(x, x2h, bias, out);
    ron_scan_kernel<<<NC * CL, 512, 0, stream>>>(h2h, gamma, eps, out, flags, chunks);
}